// Round 1
// baseline (633.508 us; speedup 1.0000x reference)
//
#include <hip/hip_runtime.h>

// Kernel A: compute starts[r] (exclusive-prefix-sum indexing) and owner[p] =
// max r mapping to absolute param p (numpy scatter: last write wins).
__global__ void compute_starts_kernel(const int* __restrict__ fields,
                                      const int* __restrict__ ppf,
                                      const int* __restrict__ sp,
                                      const int* __restrict__ coords,
                                      int R, int P_TOTAL,
                                      int* __restrict__ starts,
                                      int* __restrict__ owner) {
    int tid = threadIdx.x;
    for (int p = tid; p < P_TOTAL; p += blockDim.x) owner[p] = -1;
    __syncthreads();
    for (int r = tid; r < R; r += blockDim.x) {
        int mod   = coords[3 * r + 0];
        int field = coords[3 * r + 1];
        int par   = coords[3 * r + 2];
        int pf = 0;
        for (int m = 0; m < mod; ++m) pf += fields[m];
        int abs_field = pf + field;
        int pp = 0;
        for (int f = 0; f < abs_field; ++f) pp += ppf[f];
        int abs_param = pp + par;
        int ps = 0;
        for (int q = 0; q < abs_param; ++q) ps += sp[q];
        starts[r] = ps;
        atomicMax(&owner[abs_param], r);
    }
}

// Kernel B: gathered[r, :] = db[starts[r] : starts[r]+blk]  (original db)
__global__ void gather_kernel(const float4* __restrict__ db,
                              const int* __restrict__ starts,
                              float4* __restrict__ out,
                              int blk4) {
    int r = blockIdx.y;
    int j = blockIdx.x * blockDim.x + threadIdx.x;
    if (j >= blk4) return;
    int s4 = starts[r] >> 2;  // starts are multiples of blk (>= mult of 4)
    out[(long long)r * blk4 + j] = db[s4 + j];
}

// Kernel C: new_db block p = results[owner[p]] if covered else db block p.
// Single write per element (no copy-then-overwrite).
__global__ void scatter_merge_kernel(const float4* __restrict__ db,
                                     const float4* __restrict__ results,
                                     const int* __restrict__ owner,
                                     float4* __restrict__ newdb,
                                     int blk4) {
    int p = blockIdx.y;
    int j = blockIdx.x * blockDim.x + threadIdx.x;
    if (j >= blk4) return;
    long long i = (long long)p * blk4 + j;
    int r = owner[p];  // wave-uniform (scalar) load
    newdb[i] = (r >= 0) ? results[(long long)r * blk4 + j] : db[i];
}

extern "C" void kernel_launch(void* const* d_in, const int* in_sizes, int n_in,
                              void* d_out, int out_size, void* d_ws, size_t ws_size,
                              hipStream_t stream) {
    const float* db      = (const float*)d_in[0];
    const float* results = (const float*)d_in[1];
    const int* fields    = (const int*)d_in[2];
    const int* ppf       = (const int*)d_in[3];
    const int* sp        = (const int*)d_in[4];
    const int* coords    = (const int*)d_in[5];

    const int db_size = in_sizes[0];          // 33,554,432
    const int R       = in_sizes[5] / 3;      // 1024
    const int blk     = in_sizes[1] / R;      // 65536
    const int P_TOTAL = in_sizes[4];          // 512

    int* starts = (int*)d_ws;
    int* owner  = starts + R;

    compute_starts_kernel<<<1, 1024, 0, stream>>>(fields, ppf, sp, coords,
                                                  R, P_TOTAL, starts, owner);

    const int blk4 = blk / 4;                 // 16384 float4 per block row
    const int bx = (blk4 + 255) / 256;        // 64

    // Output 0: gathered [R, blk]
    dim3 ggrid(bx, R);
    gather_kernel<<<ggrid, 256, 0, stream>>>((const float4*)db, starts,
                                             (float4*)d_out, blk4);

    // Output 1: new_db [db_size], starts right after gathered
    float4* newdb = (float4*)d_out + (long long)R * blk4;
    dim3 sgrid(bx, P_TOTAL);
    scatter_merge_kernel<<<sgrid, 256, 0, stream>>>((const float4*)db,
                                                    (const float4*)results,
                                                    owner, newdb, blk4);
}